// Round 6
// baseline (204.329 us; speedup 1.0000x reference)
//
#include <hip/hip_runtime.h>

// Boundary_binaryLoss: 15x15 binary morphology boundary + masked NLL mean.
// B=32, C=2, H=480, W=864 (= 27*32). labels in {0,1,255}.
// valid = (lbl!=255) && window15x15 contains (v!=1) && window contains (v==1)
// loss = -sum(valid ? logits[b,lbl,h,w] : 0) / max(#valid,1)
//
// R1: atomics serialized -> partials. R2-R5: four different block-internal
// structures ALL plateau at ~63us with VALU ~34%, HBM ~25% -> the barrier/
// phase-lockstep 4-wave block is the invariant limiter, not load placement.
// R6: bit-parallel, barrier-free, LDS-free rewrite:
//   Kernel A: labels -> 1-bit masks A=(v==1), Ign=(v==255); np0 == ~A.
//   Kernel B: wave-autonomous. lane=row; horizontal 15-OR via u64 shift
//     doubling; vertical 15-OR via 6 cross-lane shuffle doublings; logits as
//     8xfloat4/lane/channel (full cache lines); per-wave partial stores.

namespace {
constexpr int B_ = 32;
constexpr int H_ = 480;
constexpr int W_ = 864;
constexpr int NW = 27;                 // mask dwords per row (864/32)
constexpr int NMASK = B_ * H_ * NW;    // 414,720 dwords = 1.66 MB per array
constexpr int SROWS = 50;              // output rows per wave (lanes 7..56)
constexpr int NSTRIP = 10;             // ceil(480/50)
constexpr int NWAVE = B_ * NW * NSTRIP;        // 8640 waves
constexpr int NBLK_B = NWAVE / 4;              // 2160 blocks
constexpr size_t OFF_IGN = 2u << 20;           // ws byte offsets
constexpr size_t OFF_PART = 4u << 20;
} // namespace

// ---------------- kernel A: bitpack labels ----------------
extern "C" __global__ __launch_bounds__(256)
void bl_bitpack(const int* __restrict__ labels,
                unsigned* __restrict__ Am, unsigned* __restrict__ Im)
{
  const int t = blockIdx.x * 256 + threadIdx.x;   // one mask dword per thread
  const int4* p = (const int4*)(labels + (size_t)t * 32);
  unsigned a = 0, ig = 0;
#pragma unroll
  for (int k = 0; k < 8; ++k) {
    const int4 v = p[k];
    a  |= ((v.x == 1)   ? 1u : 0u) << (4 * k)     | ((v.y == 1)   ? 2u : 0u) << (4 * k)
       |  ((v.z == 1)   ? 4u : 0u) << (4 * k)     | ((v.w == 1)   ? 8u : 0u) << (4 * k);
    ig |= ((v.x == 255) ? 1u : 0u) << (4 * k)     | ((v.y == 255) ? 2u : 0u) << (4 * k)
       |  ((v.z == 255) ? 4u : 0u) << (4 * k)     | ((v.w == 255) ? 8u : 0u) << (4 * k);
  }
  Am[t] = a;
  Im[t] = ig;
}

// horizontal 15-wide OR of bit-columns; w0/w1/w2 = left/center/right dwords
__device__ __forceinline__ unsigned hwin(unsigned w0, unsigned w1, unsigned w2) {
  unsigned long long L = ((unsigned long long)w1 << 32) | w0;
  unsigned long long R = ((unsigned long long)w2 << 32) | w1;
  L |= L << 1; L |= L << 2; L |= L << 4;   // bit k |= bits k-7..k
  R |= R >> 1; R |= R >> 2; R |= R >> 4;   // bit k |= bits k..k+7
  return (unsigned)(L >> 32) | (unsigned)R;
}

// vertical 15-wide OR across lanes (lane = row); halo lanes hold valid rows
__device__ __forceinline__ unsigned vwin(unsigned x) {
  unsigned u = x, d = x;
  u |= __shfl_up(u, 1, 64);  u |= __shfl_up(u, 2, 64);  u |= __shfl_up(u, 4, 64);
  d |= __shfl_down(d, 1, 64); d |= __shfl_down(d, 2, 64); d |= __shfl_down(d, 4, 64);
  return u | d;
}

// ---------------- kernel B: morphology + NLL gather ----------------
extern "C" __global__ __launch_bounds__(256)
void bl_main(const float* __restrict__ logits,
             const unsigned* __restrict__ Am, const unsigned* __restrict__ Im,
             float2* __restrict__ partials)
{
  const int tid = threadIdx.x;
  const int lane = tid & 63;
  const int wid = blockIdx.x * 4 + (tid >> 6);   // 0..8639
  const int b = wid / (NW * NSTRIP);
  const int rem = wid - b * (NW * NSTRIP);
  const int dc = rem / NSTRIP;                   // dword-column 0..26
  const int s = rem - dc * NSTRIP;               // row strip 0..9

  const int gr = SROWS * s - 7 + lane;           // this lane's row
  const bool inrow = (gr >= 0) && (gr < H_);
  const bool out_lane = (lane >= 7) && (lane <= 56) && (gr < H_);

  // ---- mask loads (3.3 MB arrays; L2/L3-resident after kernel A) ----
  unsigned A0 = 0, A1 = 0, A2 = 0, Ic = 0;
  if (inrow) {
    const size_t rbase = ((size_t)b * H_ + gr) * NW + dc;
    A1 = Am[rbase];
    Ic = Im[rbase];
    if (dc > 0) A0 = Am[rbase - 1];
    if (dc < NW - 1) A2 = Am[rbase + 1];
  }
  // np0 = ~A, but OOB rows/cols contribute nothing
  const unsigned N0 = (inrow && dc > 0) ? ~A0 : 0u;
  const unsigned N1 = inrow ? ~A1 : 0u;
  const unsigned N2 = (inrow && dc < NW - 1) ? ~A2 : 0u;

  // ---- 15x15 window OR: horizontal (u64 SWAR) then vertical (shuffles) ----
  const unsigned hA = hwin(A0, A1, A2);   // window contains v==1
  const unsigned hN = hwin(N0, N1, N2);   // window contains v!=1
  const unsigned vA = vwin(hA);
  const unsigned vN = vwin(hN);

  unsigned valid = out_lane ? (vA & vN & ~Ic) : 0u;

  // ---- logits: one full 128B line per lane per channel ----
  float lsum = 0.f;
  unsigned lcnt = 0;
  if (out_lane) {
    const size_t off = ((size_t)b * 2 * H_ + gr) * W_ + dc * 32;
    const float4* p0 = (const float4*)(logits + off);
    const float4* p1 = (const float4*)(logits + off + (size_t)H_ * W_);
    float c0[32], c1[32];
#pragma unroll
    for (int k = 0; k < 8; ++k) {
      const float4 u0 = p0[k], u1 = p1[k];
      c0[4 * k] = u0.x; c0[4 * k + 1] = u0.y; c0[4 * k + 2] = u0.z; c0[4 * k + 3] = u0.w;
      c1[4 * k] = u1.x; c1[4 * k + 1] = u1.y; c1[4 * k + 2] = u1.z; c1[4 * k + 3] = u1.w;
    }
    lcnt = __popc(valid);
#pragma unroll
    for (int k = 0; k < 32; ++k) {
      const bool vb = (valid >> k) & 1u;
      const float pick = ((A1 >> k) & 1u) ? c1[k] : c0[k];
      lsum += vb ? pick : 0.f;
    }
  }

  // ---- per-wave reduction -> one float2 per wave ----
#pragma unroll
  for (int off = 32; off > 0; off >>= 1) {
    lsum += __shfl_down(lsum, off, 64);
    lcnt += __shfl_down(lcnt, off, 64);
  }
  if (lane == 0) partials[wid] = make_float2(lsum, (float)lcnt);
}

// ---------------- final reduction ----------------
extern "C" __global__ __launch_bounds__(1024)
void bl_final(const float2* __restrict__ partials, float* __restrict__ out)
{
  __shared__ double red_s[16];
  __shared__ double red_c[16];
  const int tid = threadIdx.x;
  double s = 0.0, cc = 0.0;
  for (int i = tid; i < NWAVE; i += 1024) {
    const float2 p = partials[i];
    s += (double)p.x;
    cc += (double)p.y;
  }
#pragma unroll
  for (int off = 32; off > 0; off >>= 1) {
    s += __shfl_down(s, off, 64);
    cc += __shfl_down(cc, off, 64);
  }
  const int wave = tid >> 6;
  if ((tid & 63) == 0) { red_s[wave] = s; red_c[wave] = cc; }
  __syncthreads();
  if (tid == 0) {
    double ts = 0.0, tc = 0.0;
#pragma unroll
    for (int i = 0; i < 16; ++i) { ts += red_s[i]; tc += red_c[i]; }
    if (tc < 1.0) tc = 1.0;
    out[0] = (float)(-ts / tc);
  }
}

extern "C" void kernel_launch(void* const* d_in, const int* in_sizes, int n_in,
                              void* d_out, int out_size, void* d_ws, size_t ws_size,
                              hipStream_t stream)
{
  const float* logits = (const float*)d_in[0];
  const int* labels = (const int*)d_in[1];
  float* out = (float*)d_out;
  unsigned* Am = (unsigned*)d_ws;                          // 1.66 MB
  unsigned* Im = (unsigned*)((char*)d_ws + OFF_IGN);       // 1.66 MB
  float2* partials = (float2*)((char*)d_ws + OFF_PART);    // 69 KB
  // every ws slot used is fully written each call -> no init vs 0xAA poison

  bl_bitpack<<<NMASK / 256, 256, 0, stream>>>(labels, Am, Im);
  bl_main<<<NBLK_B, 256, 0, stream>>>(logits, Am, Im, partials);
  bl_final<<<1, 1024, 0, stream>>>(partials, out);
}